// Round 1
// baseline (8219.694 us; speedup 1.0000x reference)
//
#include <hip/hip_runtime.h>
#include <math.h>

#define NRES 8192
#define NPER 2048
#define KNB  30
#define NEDGE (NRES*KNB)

__device__ __forceinline__ float siluf(float x){ return x / (1.0f + __expf(-x)); }

// ---------------- K0: backbone features (dihedrals + vecs) -> bbf (N,4,7) ----------------
__global__ void k_bbfeat(const float* __restrict__ bb, float* __restrict__ bbf){
  int n = blockIdx.x*256 + threadIdx.x;
  if(n >= NRES) return;
  const float* r = bb + n*12;
  float cax=r[3], cay=r[4], caz=r[5];
  float vx[7],vy[7],vz[7];
  for(int a=0;a<4;a++){ vx[a]=r[a*3]-cax; vy[a]=r[a*3+1]-cay; vz[a]=r[a*3+2]-caz; }
  if(n<NRES-1){
    float dx=bb[(n+1)*12+3]-cax, dy=bb[(n+1)*12+4]-cay, dz=bb[(n+1)*12+5]-caz;
    float s=rsqrtf(dx*dx+dy*dy+dz*dz+1e-8f);
    vx[4]=dx*s; vy[4]=dy*s; vz[4]=dz*s;
  } else { vx[4]=0.f; vy[4]=0.f; vz[4]=0.f; }
  if(n>0){
    float dx=bb[(n-1)*12+3]-cax, dy=bb[(n-1)*12+4]-cay, dz=bb[(n-1)*12+5]-caz;
    float s=rsqrtf(dx*dx+dy*dy+dz*dz+1e-8f);
    vx[5]=dx*s; vy[5]=dy*s; vz[5]=dz*s;
  } else { vx[5]=0.f; vy[5]=0.f; vz[5]=0.f; }
  {
    float bx=cax-r[0], by=cay-r[1], bz=caz-r[2];
    float cx=r[6]-cax, cy=r[7]-cay, cz=r[8]-caz;
    float axx=by*cz-bz*cy, ayy=bz*cx-bx*cz, azz=bx*cy-by*cx;
    vx[6]=-0.58273431f*axx+0.56802827f*bx-0.54067466f*cx;
    vy[6]=-0.58273431f*ayy+0.56802827f*by-0.54067466f*cy;
    vz[6]=-0.58273431f*azz+0.56802827f*bz-0.54067466f*cz;
  }
  float cD[3], sD[3];
  for(int t=0;t<3;t++){
    cD[t]=1.0f; sD[t]=0.0f;
    int f=3*n+t-1;
    if(f>=0 && f<3*NRES-3){
      float X[4][3];
      for(int q=0;q<4;q++){
        int m=f+q, rr=m/3, aa=m-rr*3;
        X[q][0]=bb[rr*12+aa*3]; X[q][1]=bb[rr*12+aa*3+1]; X[q][2]=bb[rr*12+aa*3+2];
      }
      float u2x=X[1][0]-X[0][0], u2y=X[1][1]-X[0][1], u2z=X[1][2]-X[0][2];
      float u1x=X[2][0]-X[1][0], u1y=X[2][1]-X[1][1], u1z=X[2][2]-X[1][2];
      float u0x=X[3][0]-X[2][0], u0y=X[3][1]-X[2][1], u0z=X[3][2]-X[2][2];
      float s2=rsqrtf(u2x*u2x+u2y*u2y+u2z*u2z+1e-8f); u2x*=s2; u2y*=s2; u2z*=s2;
      float s1=rsqrtf(u1x*u1x+u1y*u1y+u1z*u1z+1e-8f); u1x*=s1; u1y*=s1; u1z*=s1;
      float s0=rsqrtf(u0x*u0x+u0y*u0y+u0z*u0z+1e-8f); u0x*=s0; u0y*=s0; u0z*=s0;
      float n2x=u2y*u1z-u2z*u1y, n2y=u2z*u1x-u2x*u1z, n2z=u2x*u1y-u2y*u1x;
      float nn2=rsqrtf(n2x*n2x+n2y*n2y+n2z*n2z+1e-8f); n2x*=nn2; n2y*=nn2; n2z*=nn2;
      float n1x=u1y*u0z-u1z*u0y, n1y=u1z*u0x-u1x*u0z, n1z=u1x*u0y-u1y*u0x;
      float nn1=rsqrtf(n1x*n1x+n1y*n1y+n1z*n1z+1e-8f); n1x*=nn1; n1y*=nn1; n1z*=nn1;
      float dotn = n2x*n1x+n2y*n1y+n2z*n1z;
      float cosD = fminf(fmaxf(dotn, -1.0f+1e-6f), 1.0f-1e-6f);
      float sg = u2x*n1x+u2y*n1y+u2z*n1z;
      if(sg==0.0f){ cD[t]=1.0f; sD[t]=0.0f; }
      else {
        float sgn = (sg>0.0f)?1.0f:-1.0f;
        cD[t]=cosD;
        sD[t]=sgn*sqrtf(fmaxf(1.0f-cosD*cosD,0.0f));
      }
    }
  }
  float* o = bbf + n*28;
  o[0]=cD[0]; o[1]=cD[1]; o[2]=cD[2]; o[3]=sD[0]; o[4]=sD[1]; o[5]=sD[2]; o[6]=0.f;
  for(int c=0;c<7;c++){ o[7+c]=vx[c]; o[14+c]=vy[c]; o[21+c]=vz[c]; }
}

// ---------------- K1: kNN (per-batch, top-30 smallest d2) ----------------
__global__ void k_knn(const float* __restrict__ bb, int* __restrict__ nbr){
  __shared__ float sx[NPER], sy[NPER], sz[NPER];
  int i = blockIdx.x*64 + threadIdx.x;
  int batch = (blockIdx.x*64) / NPER;
  int base = batch*NPER;
  for(int t=threadIdx.x; t<NPER; t+=64){
    int g = base+t;
    sx[t]=bb[g*12+3]; sy[t]=bb[g*12+4]; sz[t]=bb[g*12+5];
  }
  __syncthreads();
  int il = i - base;
  float xi=sx[il], yi=sy[il], zi=sz[il];
  float si = xi*xi+yi*yi+zi*zi;
  float bd[KNB]; int bi[KNB];
  for(int t=0;t<KNB;t++){ bd[t]=1e30f; bi[t]=0; }
  for(int j=0;j<NPER;j++){
    if(j==il) continue;
    float xj=sx[j], yj=sy[j], zj=sz[j];
    float d2 = si + (xj*xj+yj*yj+zj*zj) - 2.0f*(xi*xj+yi*yj+zi*zj);
    if(d2 < bd[KNB-1]){
      int p = KNB-1;
      while(p>0 && bd[p-1] > d2){ bd[p]=bd[p-1]; bi[p]=bi[p-1]; p--; }
      bd[p]=d2; bi[p]=base+j;
    }
  }
  for(int t=0;t<KNB;t++) nbr[i*KNB+t] = bi[t];
}

// ---------------- K2: edge features ef (N,k,32) = [rbf16, cos8, sin8] ----------------
__global__ void k_edgefeat(const float* __restrict__ bb, const int* __restrict__ nbr,
                           float* __restrict__ ef){
  int e = blockIdx.x*256 + threadIdx.x;
  if(e >= NEDGE) return;
  int n = e/KNB;
  int j = nbr[e];
  float dx=bb[n*12+3]-bb[j*12+3], dy=bb[n*12+4]-bb[j*12+4], dz=bb[n*12+5]-bb[j*12+5];
  float dist = sqrtf(dx*dx+dy*dy+dz*dz + 1e-12f);
  float* o = ef + (size_t)e*32;
  for(int m=0;m<16;m++){
    float mu = (20.0f/15.0f)*(float)m;
    float t = (dist-mu)*(1.0f/1.25f);
    o[m] = __expf(-t*t);
  }
  float didx = (float)(j - n);
  for(int m=0;m<8;m++){
    float freq = __expf(-1.1512925465f*(float)m);  // 10000^(-m/8)
    float ang = didx*freq;
    o[16+m]=cosf(ang); o[24+m]=sinf(ang);
  }
}

// ---------------- K3: norm_so3 (N,4,32): LN on row0, RMS on rows 1..3 ----------------
__global__ void k_norm(const float* __restrict__ in, float* __restrict__ out,
                       const float* __restrict__ g0, const float* __restrict__ b0,
                       const float* __restrict__ g1){
  int tid = blockIdx.x*256 + threadIdx.x;
  int n = tid >> 5, lane = tid & 31;
  if(n >= NRES) return;
  const float* xn = in + n*128;
  float x0 = xn[lane];
  float s = x0, s2 = x0*x0;
  for(int off=16; off>0; off>>=1){ s += __shfl_xor(s, off, 32); s2 += __shfl_xor(s2, off, 32); }
  float mu = s*(1.0f/32.0f);
  float var = s2*(1.0f/32.0f) - mu*mu;
  float y0 = (x0-mu)*rsqrtf(var+1e-6f)*g0[lane] + b0[lane];
  float v1 = xn[32+lane], v2 = xn[64+lane], v3 = xn[96+lane];
  float ss = v1*v1+v2*v2+v3*v3;
  for(int off=16; off>0; off>>=1){ ss += __shfl_xor(ss, off, 32); }
  float sc = rsqrtf(ss*(1.0f/96.0f) + 1e-6f);
  float g = g1[lane];
  out[n*128+lane]     = y0;
  out[n*128+32+lane]  = v1*sc*g;
  out[n*128+64+lane]  = v2*sc*g;
  out[n*128+96+lane]  = v3*sc*g;
}

// ---------------- K4: initial projection -> x (N,4,32) ----------------
// rot/rot_inv cancel (R orthonormal): msg = mean_k(xin[nbr]*rad); x = [msg_bb@bb_out, msg_lat@lat_out]
__global__ void k_init(const int* __restrict__ nbr, const float* __restrict__ ef,
                       const float* __restrict__ bbf, const float* __restrict__ latn,
                       const float* __restrict__ bbw1, const float* __restrict__ bbw2,
                       const float* __restrict__ bboutw,
                       const float* __restrict__ latw1, const float* __restrict__ latw2,
                       const float* __restrict__ latoutw,
                       float* __restrict__ x){
  __shared__ float efr[4][32], hbb[4][64], hlat[4][64], radbb[4][8], radlat[4][32];
  __shared__ float msgbb[4][28], msglat[4][128];
  int g = threadIdx.x>>6, t = threadIdx.x&63;
  int n = blockIdx.x*4 + g;
  float accL0=0.f, accL1=0.f, accB=0.f;
  for(int kk=0; kk<KNB; kk++){
    int e = n*KNB+kk;
    int j = nbr[e];
    if(t<32) efr[g][t] = ef[(size_t)e*32+t];
    __syncthreads();
    float hb=0.f, hl=0.f;
    for(int c=0;c<32;c++){ float v=efr[g][c]; hb += v*bbw1[c*64+t]; hl += v*latw1[c*64+t]; }
    hbb[g][t]=siluf(hb); hlat[g][t]=siluf(hl);
    __syncthreads();
    if(t<7){ float rr=0.f; for(int c=0;c<64;c++) rr += hbb[g][c]*bbw2[c*7+t]; radbb[g][t]=rr; }
    else if(t>=32){ int tt=t-32; float rr=0.f; for(int c=0;c<64;c++) rr += hlat[g][c]*latw2[c*32+tt]; radlat[g][tt]=rr; }
    __syncthreads();
    float rl = radlat[g][t&31];
    accL0 += latn[j*128+t]    * rl;
    accL1 += latn[j*128+64+t] * rl;
    if(t<28) accB += bbf[j*28+t]*radbb[g][t%7];
    __syncthreads();
  }
  if(t<28) msgbb[g][t]=accB*(1.0f/KNB);
  msglat[g][t]=accL0*(1.0f/KNB); msglat[g][64+t]=accL1*(1.0f/KNB);
  __syncthreads();
  for(int half=0; half<2; half++){
    int e = half*64+t;
    int rrow = e>>5, c = e&31;
    float v=0.f;
    if(c<16){ for(int q=0;q<7;q++)  v += msgbb[g][rrow*7+q]*bboutw[q*16+c]; }
    else    { for(int q=0;q<32;q++) v += msglat[g][rrow*32+q]*latoutw[q*16+(c-16)]; }
    x[n*128+e]=v;
  }
}

// ---------------- K5: attention logits per edge (N,k,8) ----------------
__global__ void k_logits(const int* __restrict__ nbr, const float* __restrict__ xl,
                         const float* __restrict__ ef, const float* __restrict__ w1,
                         const float* __restrict__ w2, float* __restrict__ logits){
  __shared__ float F[8][96], Hh[8][32];
  int g = threadIdx.x>>5, lane = threadIdx.x&31;
  int e = blockIdx.x*8 + g;
  int n = e/KNB;
  int j = nbr[e];
  F[g][lane]    = xl[j*128+lane];
  F[g][32+lane] = xl[n*128+lane];
  F[g][64+lane] = ef[(size_t)e*32+lane];
  __syncthreads();
  float h=0.f;
  for(int c=0;c<96;c++) h += F[g][c]*w1[c*32+lane];
  Hh[g][lane]=siluf(h);
  __syncthreads();
  if(lane<8){
    float lo=0.f;
    for(int c=0;c<32;c++) lo += Hh[g][c]*w2[c*8+lane];
    logits[(size_t)e*8+lane]=lo;
  }
}

// ---------------- K6: softmax over k, in place ----------------
__global__ void k_softmax(float* __restrict__ lg){
  int tid = blockIdx.x*256 + threadIdx.x;
  if(tid >= NRES*8) return;
  int n = tid>>3, h = tid&7;
  size_t base = (size_t)n*KNB*8 + h;
  float m=-1e30f;
  for(int kk=0;kk<KNB;kk++){ float v=lg[base+kk*8]; m=fmaxf(m,v); }
  float s=0.f;
  for(int kk=0;kk<KNB;kk++){ s += __expf(lg[base+kk*8]-m); }
  float inv = 1.0f/s;
  for(int kk=0;kk<KNB;kk++){ lg[base+kk*8] = __expf(lg[base+kk*8]-m)*inv; }
}

// ---------------- K7: aggregate heads + o_w + FFN -> x (in place) ----------------
__global__ void k_update(const int* __restrict__ nbr, const float* __restrict__ xl,
                         const float* __restrict__ alpha, float* __restrict__ x,
                         const float* __restrict__ vw, const float* __restrict__ ow,
                         const float* __restrict__ fw1, const float* __restrict__ fw2,
                         const float* __restrict__ fwg, const float* __restrict__ fv1){
  __shared__ float S_xl[4][128], S_S[4][1024], S_agg[4][512], S_x[4][128];
  __shared__ float S_h[4][64], S_g[4][32], S_d0[4][32];
  int g = threadIdx.x>>6, t = threadIdx.x&63;
  int n = blockIdx.x*4 + g;
  int hd = t>>3, i8 = t&7;
  float acc[16];
  for(int m=0;m<16;m++) acc[m]=0.f;
  for(int kk=0;kk<KNB;kk++){
    int e=n*KNB+kk;
    int j=nbr[e];
    S_xl[g][t]    = xl[j*128+t];
    S_xl[g][64+t] = xl[j*128+64+t];
    __syncthreads();
    float a = alpha[(size_t)e*8+hd];
    for(int m=0;m<16;m++) acc[m] += a * S_xl[g][i8*16+m];
    __syncthreads();
  }
  for(int m=0;m<16;m++) S_S[g][hd*128 + i8*16 + m] = acc[m];
  __syncthreads();
  // agg = S_h @ v_w (per-head 32->16 slices), cols hv = t, 64+t
  for(int half=0; half<2; half++){
    int hv = half*64+t;
    int hh = hv>>4;
    float a0=0.f,a1=0.f,a2=0.f,a3=0.f;
    for(int c=0;c<32;c++){
      float w = vw[c*128+hv];
      a0 += S_S[g][hh*128 + c]*w;
      a1 += S_S[g][hh*128 + 32+c]*w;
      a2 += S_S[g][hh*128 + 64+c]*w;
      a3 += S_S[g][hh*128 + 96+c]*w;
    }
    S_agg[g][hv]=a0; S_agg[g][128+hv]=a1; S_agg[g][256+hv]=a2; S_agg[g][384+hv]=a3;
  }
  __syncthreads();
  // x += agg @ o_w
  for(int half=0; half<2; half++){
    int e = half*64+t;
    int rrow = e>>5, c = e&31;
    float v = x[n*128+e];
    for(int hv=0;hv<128;hv++) v += S_agg[g][rrow*128+hv]*ow[hv*32+c];
    S_x[g][e]=v;
  }
  __syncthreads();
  // FFN
  {
    float hs=0.f;
    for(int c=0;c<32;c++) hs += S_x[g][c]*fw1[c*64+t];
    S_h[g][t]=siluf(hs);
  }
  __syncthreads();
  if(t<32){
    float gs=0.f, d0=0.f;
    for(int c=0;c<64;c++){ float hv=S_h[g][c]; gs += hv*fwg[c*32+t]; d0 += hv*fw2[c*32+t]; }
    S_g[g][t]=1.0f/(1.0f+__expf(-gs));
    S_d0[g][t]=d0;
  }
  __syncthreads();
  for(int half=0; half<2; half++){
    int e = half*64+t;
    int rrow = e>>5, c = e&31;
    float xv = S_x[g][e], outv;
    if(rrow==0){ outv = xv + S_d0[g][c]; }
    else {
      float dv=0.f;
      for(int cc=0;cc<32;cc++) dv += S_x[g][rrow*32+cc]*fv1[cc*32+c];
      outv = xv + dv*S_g[g][c];
    }
    x[n*128+e]=outv;
  }
}

// ---------------- K8: edge update ef += mlp([ef, x_nbr0, x_self0]) ----------------
__global__ void k_efup(const int* __restrict__ nbr, const float* __restrict__ x,
                       const float* __restrict__ ew1, const float* __restrict__ ew2,
                       float* __restrict__ ef){
  __shared__ float E[4][96], Hh[4][64];
  int g = threadIdx.x>>6, t = threadIdx.x&63;
  int e = blockIdx.x*4 + g;
  int n = e/KNB;
  int j = nbr[e];
  if(t<32){
    E[g][t]    = ef[(size_t)e*32+t];
    E[g][32+t] = x[j*128+t];
    E[g][64+t] = x[n*128+t];
  }
  __syncthreads();
  float h=0.f;
  for(int c=0;c<96;c++) h += E[g][c]*ew1[c*64+t];
  Hh[g][t]=siluf(h);
  __syncthreads();
  if(t<32){
    float s=0.f;
    for(int c=0;c<64;c++) s += Hh[g][c]*ew2[c*32+t];
    ef[(size_t)e*32+t] += s;
  }
}

// ---------------- K9: output projection -> decoded_latent (N,91,3) ----------------
__global__ void k_out(const int* __restrict__ nbr, const float* __restrict__ ef,
                      const float* __restrict__ x,
                      const float* __restrict__ orw1, const float* __restrict__ orw2,
                      const float* __restrict__ outw, float* __restrict__ out){
  __shared__ float efr[4][32], hs[4][64], rads[4][32], msg[4][128];
  int g = threadIdx.x>>6, t = threadIdx.x&63;
  int n = blockIdx.x*4 + g;
  float acc0=0.f, acc1=0.f;
  for(int kk=0;kk<KNB;kk++){
    int e=n*KNB+kk;
    int j=nbr[e];
    if(t<32) efr[g][t]=ef[(size_t)e*32+t];
    __syncthreads();
    float hh=0.f;
    for(int c=0;c<32;c++) hh += efr[g][c]*orw1[c*64+t];
    hs[g][t]=siluf(hh);
    __syncthreads();
    if(t<32){ float rr=0.f; for(int c=0;c<64;c++) rr += hs[g][c]*orw2[c*32+t]; rads[g][t]=rr; }
    __syncthreads();
    float rl = rads[g][t&31];
    acc0 += x[j*128+t]*rl;
    acc1 += x[j*128+64+t]*rl;
    __syncthreads();
  }
  msg[g][t]=acc0*(1.0f/KNB); msg[g][64+t]=acc1*(1.0f/KNB);
  __syncthreads();
  for(int o=t;o<91;o+=64){
    for(int rrow=1;rrow<4;rrow++){
      float s=0.f;
      for(int c=0;c<32;c++) s += msg[g][rrow*32+c]*outw[c*91+o];
      out[(size_t)n*273 + o*3 + (rrow-1)] = s;
    }
  }
}

// ---------------- K10: sequence head -> log_softmax (N,20) ----------------
__global__ void k_seq(const float* __restrict__ x,
                      const float* __restrict__ sw1, const float* __restrict__ sb1,
                      const float* __restrict__ sw2, const float* __restrict__ sb2,
                      const float* __restrict__ sw3, const float* __restrict__ sb3,
                      float* __restrict__ out){
  __shared__ float h1[4][64], h2[4][32], lgs[4][20];
  int g = threadIdx.x>>6, t = threadIdx.x&63;
  int n = blockIdx.x*4 + g;
  {
    float s=0.f;
    for(int c=0;c<32;c++) s += x[n*128+c]*sw1[c*64+t];
    h1[g][t]=fmaxf(s+sb1[t],0.f);
  }
  __syncthreads();
  if(t<32){
    float s=0.f;
    for(int c=0;c<64;c++) s += h1[g][c]*sw2[c*32+t];
    h2[g][t]=fmaxf(s+sb2[t],0.f);
  }
  __syncthreads();
  if(t<20){
    float s=0.f;
    for(int c=0;c<32;c++) s += h2[g][c]*sw3[c*20+t];
    lgs[g][t]=s+sb3[t];
  }
  __syncthreads();
  if(t<20){
    float m=-1e30f;
    for(int c=0;c<20;c++) m=fmaxf(m,lgs[g][c]);
    float se=0.f;
    for(int c=0;c<20;c++) se += expf(lgs[g][c]-m);
    out[(size_t)n*20+t]=lgs[g][t]-m-logf(se);
  }
}

extern "C" void kernel_launch(void* const* d_in, const int* in_sizes, int n_in,
                              void* d_out, int out_size, void* d_ws, size_t ws_size,
                              hipStream_t stream) {
  const float* bb      = (const float*)d_in[0];
  const float* latent  = (const float*)d_in[1];
  const float* ln_g0   = (const float*)d_in[2];
  const float* ln_b0   = (const float*)d_in[3];
  const float* ln_g1   = (const float*)d_in[4];
  const float* bbw1    = (const float*)d_in[5];
  const float* bbw2    = (const float*)d_in[6];
  const float* bboutw  = (const float*)d_in[7];
  const float* latw1   = (const float*)d_in[8];
  const float* latw2   = (const float*)d_in[9];
  const float* latoutw = (const float*)d_in[10];
  const float* tg0     = (const float*)d_in[11];
  const float* tb0     = (const float*)d_in[12];
  const float* tg1     = (const float*)d_in[13];
  const float* aw1     = (const float*)d_in[14];
  const float* aw2     = (const float*)d_in[15];
  const float* vw      = (const float*)d_in[16];
  const float* ow      = (const float*)d_in[17];
  const float* fw1     = (const float*)d_in[18];
  const float* fw2     = (const float*)d_in[19];
  const float* fwg     = (const float*)d_in[20];
  const float* fv1     = (const float*)d_in[21];
  const float* ew1     = (const float*)d_in[22];
  const float* ew2     = (const float*)d_in[23];
  const float* orw1    = (const float*)d_in[24];
  const float* orw2    = (const float*)d_in[25];
  const float* outw    = (const float*)d_in[26];
  const float* sw1     = (const float*)d_in[27];
  const float* sb1     = (const float*)d_in[28];
  const float* sw2     = (const float*)d_in[29];
  const float* sb2     = (const float*)d_in[30];
  const float* sw3     = (const float*)d_in[31];
  const float* sb3     = (const float*)d_in[32];
  float* outp = (float*)d_out;

  // workspace layout
  int*   nbr    = (int*)d_ws;
  float* ef     = (float*)((char*)d_ws + 1024*1024);
  float* xbuf   = ef   + (size_t)NEDGE*32;
  float* xl     = xbuf + (size_t)NRES*128;
  float* bbf    = xl   + (size_t)NRES*128;
  float* logits = bbf  + (size_t)NRES*28;

  k_bbfeat  <<<NRES/256, 256, 0, stream>>>(bb, bbf);
  k_knn     <<<NRES/64,   64, 0, stream>>>(bb, nbr);
  k_edgefeat<<<NEDGE/256, 256, 0, stream>>>(bb, nbr, ef);
  k_norm    <<<NRES*32/256, 256, 0, stream>>>(latent, xl, ln_g0, ln_b0, ln_g1);
  k_init    <<<NRES/4, 256, 0, stream>>>(nbr, ef, bbf, xl, bbw1, bbw2, bboutw,
                                         latw1, latw2, latoutw, xbuf);
  for(int l=0;l<4;l++){
    k_norm   <<<NRES*32/256, 256, 0, stream>>>(xbuf, xl, tg0+l*32, tb0+l*32, tg1+l*32);
    k_logits <<<NEDGE/8, 256, 0, stream>>>(nbr, xl, ef, aw1+l*96*32, aw2+l*32*8, logits);
    k_softmax<<<NRES*8/256, 256, 0, stream>>>(logits);
    k_update <<<NRES/4, 256, 0, stream>>>(nbr, xl, logits, xbuf,
                                          vw+l*32*128, ow+l*128*32,
                                          fw1+l*32*64, fw2+l*64*32,
                                          fwg+l*64*32, fv1+l*32*32);
    k_efup   <<<NEDGE/4, 256, 0, stream>>>(nbr, xbuf, ew1+l*96*64, ew2+l*64*32, ef);
  }
  k_out<<<NRES/4, 256, 0, stream>>>(nbr, ef, xbuf, orw1, orw2, outw, outp);
  k_seq<<<NRES/4, 256, 0, stream>>>(xbuf, sw1, sb1, sw2, sb2, sw3, sb3,
                                    outp + (size_t)NRES*273);
}

// Round 2
// 3466.362 us; speedup vs baseline: 2.3713x; 2.3713x over previous
//
#include <hip/hip_runtime.h>
#include <math.h>

#define NRES 8192
#define NPER 2048
#define KNB  30
#define NEDGE (NRES*KNB)

__device__ __forceinline__ float siluf(float x){ return x / (1.0f + __expf(-x)); }

// ---------------- K-1: pack Ca coords + |x|^2 into contiguous float4 ----------------
__global__ void k_pack(const float* __restrict__ bb, float4* __restrict__ ca){
  int n = blockIdx.x*256 + threadIdx.x;
  if(n >= NRES) return;
  float x=bb[n*12+3], y=bb[n*12+4], z=bb[n*12+5];
  ca[n] = make_float4(x,y,z, x*x+y*y+z*z);
}

// ---------------- K0: backbone features (dihedrals + vecs) -> bbf (N,4,7) ----------------
__global__ void k_bbfeat(const float* __restrict__ bb, float* __restrict__ bbf){
  int n = blockIdx.x*256 + threadIdx.x;
  if(n >= NRES) return;
  const float* r = bb + n*12;
  float cax=r[3], cay=r[4], caz=r[5];
  float vx[7],vy[7],vz[7];
  for(int a=0;a<4;a++){ vx[a]=r[a*3]-cax; vy[a]=r[a*3+1]-cay; vz[a]=r[a*3+2]-caz; }
  if(n<NRES-1){
    float dx=bb[(n+1)*12+3]-cax, dy=bb[(n+1)*12+4]-cay, dz=bb[(n+1)*12+5]-caz;
    float s=rsqrtf(dx*dx+dy*dy+dz*dz+1e-8f);
    vx[4]=dx*s; vy[4]=dy*s; vz[4]=dz*s;
  } else { vx[4]=0.f; vy[4]=0.f; vz[4]=0.f; }
  if(n>0){
    float dx=bb[(n-1)*12+3]-cax, dy=bb[(n-1)*12+4]-cay, dz=bb[(n-1)*12+5]-caz;
    float s=rsqrtf(dx*dx+dy*dy+dz*dz+1e-8f);
    vx[5]=dx*s; vy[5]=dy*s; vz[5]=dz*s;
  } else { vx[5]=0.f; vy[5]=0.f; vz[5]=0.f; }
  {
    float bx=cax-r[0], by=cay-r[1], bz=caz-r[2];
    float cx=r[6]-cax, cy=r[7]-cay, cz=r[8]-caz;
    float axx=by*cz-bz*cy, ayy=bz*cx-bx*cz, azz=bx*cy-by*cx;
    vx[6]=-0.58273431f*axx+0.56802827f*bx-0.54067466f*cx;
    vy[6]=-0.58273431f*ayy+0.56802827f*by-0.54067466f*cy;
    vz[6]=-0.58273431f*azz+0.56802827f*bz-0.54067466f*cz;
  }
  float cD[3], sD[3];
  for(int t=0;t<3;t++){
    cD[t]=1.0f; sD[t]=0.0f;
    int f=3*n+t-1;
    if(f>=0 && f<3*NRES-3){
      float X[4][3];
      for(int q=0;q<4;q++){
        int m=f+q, rr=m/3, aa=m-rr*3;
        X[q][0]=bb[rr*12+aa*3]; X[q][1]=bb[rr*12+aa*3+1]; X[q][2]=bb[rr*12+aa*3+2];
      }
      float u2x=X[1][0]-X[0][0], u2y=X[1][1]-X[0][1], u2z=X[1][2]-X[0][2];
      float u1x=X[2][0]-X[1][0], u1y=X[2][1]-X[1][1], u1z=X[2][2]-X[1][2];
      float u0x=X[3][0]-X[2][0], u0y=X[3][1]-X[2][1], u0z=X[3][2]-X[2][2];
      float s2=rsqrtf(u2x*u2x+u2y*u2y+u2z*u2z+1e-8f); u2x*=s2; u2y*=s2; u2z*=s2;
      float s1=rsqrtf(u1x*u1x+u1y*u1y+u1z*u1z+1e-8f); u1x*=s1; u1y*=s1; u1z*=s1;
      float s0=rsqrtf(u0x*u0x+u0y*u0y+u0z*u0z+1e-8f); u0x*=s0; u0y*=s0; u0z*=s0;
      float n2x=u2y*u1z-u2z*u1y, n2y=u2z*u1x-u2x*u1z, n2z=u2x*u1y-u2y*u1x;
      float nn2=rsqrtf(n2x*n2x+n2y*n2y+n2z*n2z+1e-8f); n2x*=nn2; n2y*=nn2; n2z*=nn2;
      float n1x=u1y*u0z-u1z*u0y, n1y=u1z*u0x-u1x*u0z, n1z=u1x*u0y-u1y*u0x;
      float nn1=rsqrtf(n1x*n1x+n1y*n1y+n1z*n1z+1e-8f); n1x*=nn1; n1y*=nn1; n1z*=nn1;
      float dotn = n2x*n1x+n2y*n1y+n2z*n1z;
      float cosD = fminf(fmaxf(dotn, -1.0f+1e-6f), 1.0f-1e-6f);
      float sg = u2x*n1x+u2y*n1y+u2z*n1z;
      if(sg==0.0f){ cD[t]=1.0f; sD[t]=0.0f; }
      else {
        float sgn = (sg>0.0f)?1.0f:-1.0f;
        cD[t]=cosD;
        sD[t]=sgn*sqrtf(fmaxf(1.0f-cosD*cosD,0.0f));
      }
    }
  }
  float* o = bbf + n*28;
  o[0]=cD[0]; o[1]=cD[1]; o[2]=cD[2]; o[3]=sD[0]; o[4]=sD[1]; o[5]=sD[2]; o[6]=0.f;
  for(int c=0;c<7;c++){ o[7+c]=vx[c]; o[14+c]=vy[c]; o[21+c]=vz[c]; }
}

// ---------------- K1: kNN — wave-per-query, LDS-staged coords ----------------
__global__ __launch_bounds__(256) void k_knn(const float4* __restrict__ ca, int* __restrict__ nbr){
  __shared__ float sx[NPER], sy[NPER], sz[NPER], sq[NPER];
  int wave = threadIdx.x>>6;
  int lane = threadIdx.x&63;
  int i = blockIdx.x*4 + wave;          // query index; 4 | 2048 so same batch per block
  int batch = i / NPER;
  int base = batch*NPER;
  for(int t=threadIdx.x; t<NPER; t+=256){
    float4 c = ca[base+t];
    sx[t]=c.x; sy[t]=c.y; sz[t]=c.z; sq[t]=c.w;
  }
  __syncthreads();
  int il = i - base;
  float xi=sx[il], yi=sy[il], zi=sz[il], si=sq[il];
  float vals[32];
  float lmin = 1e30f; int larg = 0;
  #pragma unroll
  for(int t=0;t<32;t++){
    int j = t*64 + lane;                // lane-adjacent j -> conflict-free LDS
    float d2 = si + sq[j] - 2.0f*(xi*sx[j]+yi*sy[j]+zi*sz[j]);
    if(j==il) d2 = 1e30f;
    vals[t]=d2;
    if(d2 < lmin){ lmin=d2; larg=t; }
  }
  for(int it=0; it<KNB; it++){
    float v = lmin; int jg = larg*64 + lane;
    #pragma unroll
    for(int off=32; off>0; off>>=1){
      float vo = __shfl_xor(v, off, 64);
      int   jo = __shfl_xor(jg, off, 64);
      if(vo < v || (vo==v && jo<jg)){ v=vo; jg=jo; }   // (d2, j) lexicographic: top_k tie-break
    }
    if(lane==0) nbr[i*KNB+it] = base + jg;
    if((jg&63)==lane){
      int targ = jg>>6;
      lmin = 1e30f; larg = 0;
      #pragma unroll
      for(int t=0;t<32;t++){
        if(t==targ) vals[t]=1e30f;
        if(vals[t]<lmin){ lmin=vals[t]; larg=t; }
      }
    }
  }
}

// ---------------- K2: edge features ef (N,k,32) = [rbf16, cos8, sin8] ----------------
__global__ void k_edgefeat(const float4* __restrict__ ca, const int* __restrict__ nbr,
                           float* __restrict__ ef){
  int e = blockIdx.x*256 + threadIdx.x;
  if(e >= NEDGE) return;
  int n = e/KNB;
  int j = nbr[e];
  float4 cn = ca[n], cj = ca[j];
  float dx=cn.x-cj.x, dy=cn.y-cj.y, dz=cn.z-cj.z;
  float dist = sqrtf(dx*dx+dy*dy+dz*dz + 1e-12f);
  float* o = ef + (size_t)e*32;
  for(int m=0;m<16;m++){
    float mu = (20.0f/15.0f)*(float)m;
    float t = (dist-mu)*(1.0f/1.25f);
    o[m] = __expf(-t*t);
  }
  float didx = (float)(j - n);
  for(int m=0;m<8;m++){
    float freq = __expf(-1.1512925465f*(float)m);  // 10000^(-m/8)
    float ang = didx*freq;
    o[16+m]=cosf(ang); o[24+m]=sinf(ang);
  }
}

// ---------------- K3: norm_so3 (N,4,32): LN on row0, RMS on rows 1..3 ----------------
__global__ void k_norm(const float* __restrict__ in, float* __restrict__ out,
                       const float* __restrict__ g0, const float* __restrict__ b0,
                       const float* __restrict__ g1){
  int tid = blockIdx.x*256 + threadIdx.x;
  int n = tid >> 5, lane = tid & 31;
  if(n >= NRES) return;
  const float* xn = in + n*128;
  float x0 = xn[lane];
  float s = x0, s2 = x0*x0;
  for(int off=16; off>0; off>>=1){ s += __shfl_xor(s, off, 32); s2 += __shfl_xor(s2, off, 32); }
  float mu = s*(1.0f/32.0f);
  float var = s2*(1.0f/32.0f) - mu*mu;
  float y0 = (x0-mu)*rsqrtf(var+1e-6f)*g0[lane] + b0[lane];
  float v1 = xn[32+lane], v2 = xn[64+lane], v3 = xn[96+lane];
  float ss = v1*v1+v2*v2+v3*v3;
  for(int off=16; off>0; off>>=1){ ss += __shfl_xor(ss, off, 32); }
  float sc = rsqrtf(ss*(1.0f/96.0f) + 1e-6f);
  float g = g1[lane];
  out[n*128+lane]     = y0;
  out[n*128+32+lane]  = v1*sc*g;
  out[n*128+64+lane]  = v2*sc*g;
  out[n*128+96+lane]  = v3*sc*g;
}

// ---------------- K4: initial projection -> x (N,4,32) ----------------
__global__ void k_init(const int* __restrict__ nbr, const float* __restrict__ ef,
                       const float* __restrict__ bbf, const float* __restrict__ latn,
                       const float* __restrict__ bbw1, const float* __restrict__ bbw2,
                       const float* __restrict__ bboutw,
                       const float* __restrict__ latw1, const float* __restrict__ latw2,
                       const float* __restrict__ latoutw,
                       float* __restrict__ x){
  __shared__ float efr[4][32], hbb[4][64], hlat[4][64], radbb[4][8], radlat[4][32];
  __shared__ float msgbb[4][28], msglat[4][128];
  int g = threadIdx.x>>6, t = threadIdx.x&63;
  int n = blockIdx.x*4 + g;
  float accL0=0.f, accL1=0.f, accB=0.f;
  for(int kk=0; kk<KNB; kk++){
    int e = n*KNB+kk;
    int j = nbr[e];
    if(t<32) efr[g][t] = ef[(size_t)e*32+t];
    __syncthreads();
    float hb=0.f, hl=0.f;
    for(int c=0;c<32;c++){ float v=efr[g][c]; hb += v*bbw1[c*64+t]; hl += v*latw1[c*64+t]; }
    hbb[g][t]=siluf(hb); hlat[g][t]=siluf(hl);
    __syncthreads();
    if(t<7){ float rr=0.f; for(int c=0;c<64;c++) rr += hbb[g][c]*bbw2[c*7+t]; radbb[g][t]=rr; }
    else if(t>=32){ int tt=t-32; float rr=0.f; for(int c=0;c<64;c++) rr += hlat[g][c]*latw2[c*32+tt]; radlat[g][tt]=rr; }
    __syncthreads();
    float rl = radlat[g][t&31];
    accL0 += latn[j*128+t]    * rl;
    accL1 += latn[j*128+64+t] * rl;
    if(t<28) accB += bbf[j*28+t]*radbb[g][t%7];
    __syncthreads();
  }
  if(t<28) msgbb[g][t]=accB*(1.0f/KNB);
  msglat[g][t]=accL0*(1.0f/KNB); msglat[g][64+t]=accL1*(1.0f/KNB);
  __syncthreads();
  for(int half=0; half<2; half++){
    int e = half*64+t;
    int rrow = e>>5, c = e&31;
    float v=0.f;
    if(c<16){ for(int q=0;q<7;q++)  v += msgbb[g][rrow*7+q]*bboutw[q*16+c]; }
    else    { for(int q=0;q<32;q++) v += msglat[g][rrow*32+q]*latoutw[q*16+(c-16)]; }
    x[n*128+e]=v;
  }
}

// ---------------- K5: attention logits per edge (N,k,8) ----------------
__global__ void k_logits(const int* __restrict__ nbr, const float* __restrict__ xl,
                         const float* __restrict__ ef, const float* __restrict__ w1,
                         const float* __restrict__ w2, float* __restrict__ logits){
  __shared__ float F[8][96], Hh[8][32];
  int g = threadIdx.x>>5, lane = threadIdx.x&31;
  int e = blockIdx.x*8 + g;
  int n = e/KNB;
  int j = nbr[e];
  F[g][lane]    = xl[j*128+lane];
  F[g][32+lane] = xl[n*128+lane];
  F[g][64+lane] = ef[(size_t)e*32+lane];
  __syncthreads();
  float h=0.f;
  for(int c=0;c<96;c++) h += F[g][c]*w1[c*32+lane];
  Hh[g][lane]=siluf(h);
  __syncthreads();
  if(lane<8){
    float lo=0.f;
    for(int c=0;c<32;c++) lo += Hh[g][c]*w2[c*8+lane];
    logits[(size_t)e*8+lane]=lo;
  }
}

// ---------------- K6: softmax over k, in place ----------------
__global__ void k_softmax(float* __restrict__ lg){
  int tid = blockIdx.x*256 + threadIdx.x;
  if(tid >= NRES*8) return;
  int n = tid>>3, h = tid&7;
  size_t base = (size_t)n*KNB*8 + h;
  float m=-1e30f;
  for(int kk=0;kk<KNB;kk++){ float v=lg[base+kk*8]; m=fmaxf(m,v); }
  float s=0.f;
  for(int kk=0;kk<KNB;kk++){ s += __expf(lg[base+kk*8]-m); }
  float inv = 1.0f/s;
  for(int kk=0;kk<KNB;kk++){ lg[base+kk*8] = __expf(lg[base+kk*8]-m)*inv; }
}

// ---------------- K7: aggregate heads + o_w + FFN -> x (in place) ----------------
__global__ void k_update(const int* __restrict__ nbr, const float* __restrict__ xl,
                         const float* __restrict__ alpha, float* __restrict__ x,
                         const float* __restrict__ vw, const float* __restrict__ ow,
                         const float* __restrict__ fw1, const float* __restrict__ fw2,
                         const float* __restrict__ fwg, const float* __restrict__ fv1){
  __shared__ float S_xl[4][128], S_S[4][1024], S_agg[4][512], S_x[4][128];
  __shared__ float S_h[4][64], S_g[4][32], S_d0[4][32];
  int g = threadIdx.x>>6, t = threadIdx.x&63;
  int n = blockIdx.x*4 + g;
  int hd = t>>3, i8 = t&7;
  float acc[16];
  for(int m=0;m<16;m++) acc[m]=0.f;
  for(int kk=0;kk<KNB;kk++){
    int e=n*KNB+kk;
    int j=nbr[e];
    S_xl[g][t]    = xl[j*128+t];
    S_xl[g][64+t] = xl[j*128+64+t];
    __syncthreads();
    float a = alpha[(size_t)e*8+hd];
    for(int m=0;m<16;m++) acc[m] += a * S_xl[g][i8*16+m];
    __syncthreads();
  }
  for(int m=0;m<16;m++) S_S[g][hd*128 + i8*16 + m] = acc[m];
  __syncthreads();
  for(int half=0; half<2; half++){
    int hv = half*64+t;
    int hh = hv>>4;
    float a0=0.f,a1=0.f,a2=0.f,a3=0.f;
    for(int c=0;c<32;c++){
      float w = vw[c*128+hv];
      a0 += S_S[g][hh*128 + c]*w;
      a1 += S_S[g][hh*128 + 32+c]*w;
      a2 += S_S[g][hh*128 + 64+c]*w;
      a3 += S_S[g][hh*128 + 96+c]*w;
    }
    S_agg[g][hv]=a0; S_agg[g][128+hv]=a1; S_agg[g][256+hv]=a2; S_agg[g][384+hv]=a3;
  }
  __syncthreads();
  for(int half=0; half<2; half++){
    int e = half*64+t;
    int rrow = e>>5, c = e&31;
    float v = x[n*128+e];
    for(int hv=0;hv<128;hv++) v += S_agg[g][rrow*128+hv]*ow[hv*32+c];
    S_x[g][e]=v;
  }
  __syncthreads();
  {
    float hs=0.f;
    for(int c=0;c<32;c++) hs += S_x[g][c]*fw1[c*64+t];
    S_h[g][t]=siluf(hs);
  }
  __syncthreads();
  if(t<32){
    float gs=0.f, d0=0.f;
    for(int c=0;c<64;c++){ float hv=S_h[g][c]; gs += hv*fwg[c*32+t]; d0 += hv*fw2[c*32+t]; }
    S_g[g][t]=1.0f/(1.0f+__expf(-gs));
    S_d0[g][t]=d0;
  }
  __syncthreads();
  for(int half=0; half<2; half++){
    int e = half*64+t;
    int rrow = e>>5, c = e&31;
    float xv = S_x[g][e], outv;
    if(rrow==0){ outv = xv + S_d0[g][c]; }
    else {
      float dv=0.f;
      for(int cc=0;cc<32;cc++) dv += S_x[g][rrow*32+cc]*fv1[cc*32+c];
      outv = xv + dv*S_g[g][c];
    }
    x[n*128+e]=outv;
  }
}

// ---------------- K8: edge update ef += mlp([ef, x_nbr0, x_self0]) ----------------
__global__ void k_efup(const int* __restrict__ nbr, const float* __restrict__ x,
                       const float* __restrict__ ew1, const float* __restrict__ ew2,
                       float* __restrict__ ef){
  __shared__ float E[4][96], Hh[4][64];
  int g = threadIdx.x>>6, t = threadIdx.x&63;
  int e = blockIdx.x*4 + g;
  int n = e/KNB;
  int j = nbr[e];
  if(t<32){
    E[g][t]    = ef[(size_t)e*32+t];
    E[g][32+t] = x[j*128+t];
    E[g][64+t] = x[n*128+t];
  }
  __syncthreads();
  float h=0.f;
  for(int c=0;c<96;c++) h += E[g][c]*ew1[c*64+t];
  Hh[g][t]=siluf(h);
  __syncthreads();
  if(t<32){
    float s=0.f;
    for(int c=0;c<64;c++) s += Hh[g][c]*ew2[c*32+t];
    ef[(size_t)e*32+t] += s;
  }
}

// ---------------- K9: output projection -> decoded_latent (N,91,3) ----------------
__global__ void k_out(const int* __restrict__ nbr, const float* __restrict__ ef,
                      const float* __restrict__ x,
                      const float* __restrict__ orw1, const float* __restrict__ orw2,
                      const float* __restrict__ outw, float* __restrict__ out){
  __shared__ float efr[4][32], hs[4][64], rads[4][32], msg[4][128];
  int g = threadIdx.x>>6, t = threadIdx.x&63;
  int n = blockIdx.x*4 + g;
  float acc0=0.f, acc1=0.f;
  for(int kk=0;kk<KNB;kk++){
    int e=n*KNB+kk;
    int j=nbr[e];
    if(t<32) efr[g][t]=ef[(size_t)e*32+t];
    __syncthreads();
    float hh=0.f;
    for(int c=0;c<32;c++) hh += efr[g][c]*orw1[c*64+t];
    hs[g][t]=siluf(hh);
    __syncthreads();
    if(t<32){ float rr=0.f; for(int c=0;c<64;c++) rr += hs[g][c]*orw2[c*32+t]; rads[g][t]=rr; }
    __syncthreads();
    float rl = rads[g][t&31];
    acc0 += x[j*128+t]*rl;
    acc1 += x[j*128+64+t]*rl;
    __syncthreads();
  }
  msg[g][t]=acc0*(1.0f/KNB); msg[g][64+t]=acc1*(1.0f/KNB);
  __syncthreads();
  for(int o=t;o<91;o+=64){
    for(int rrow=1;rrow<4;rrow++){
      float s=0.f;
      for(int c=0;c<32;c++) s += msg[g][rrow*32+c]*outw[c*91+o];
      out[(size_t)n*273 + o*3 + (rrow-1)] = s;
    }
  }
}

// ---------------- K10: sequence head -> log_softmax (N,20) ----------------
__global__ void k_seq(const float* __restrict__ x,
                      const float* __restrict__ sw1, const float* __restrict__ sb1,
                      const float* __restrict__ sw2, const float* __restrict__ sb2,
                      const float* __restrict__ sw3, const float* __restrict__ sb3,
                      float* __restrict__ out){
  __shared__ float h1[4][64], h2[4][32], lgs[4][20];
  int g = threadIdx.x>>6, t = threadIdx.x&63;
  int n = blockIdx.x*4 + g;
  {
    float s=0.f;
    for(int c=0;c<32;c++) s += x[n*128+c]*sw1[c*64+t];
    h1[g][t]=fmaxf(s+sb1[t],0.f);
  }
  __syncthreads();
  if(t<32){
    float s=0.f;
    for(int c=0;c<64;c++) s += h1[g][c]*sw2[c*32+t];
    h2[g][t]=fmaxf(s+sb2[t],0.f);
  }
  __syncthreads();
  if(t<20){
    float s=0.f;
    for(int c=0;c<32;c++) s += h2[g][c]*sw3[c*20+t];
    lgs[g][t]=s+sb3[t];
  }
  __syncthreads();
  if(t<20){
    float m=-1e30f;
    for(int c=0;c<20;c++) m=fmaxf(m,lgs[g][c]);
    float se=0.f;
    for(int c=0;c<20;c++) se += expf(lgs[g][c]-m);
    out[(size_t)n*20+t]=lgs[g][t]-m-logf(se);
  }
}

extern "C" void kernel_launch(void* const* d_in, const int* in_sizes, int n_in,
                              void* d_out, int out_size, void* d_ws, size_t ws_size,
                              hipStream_t stream) {
  const float* bb      = (const float*)d_in[0];
  const float* latent  = (const float*)d_in[1];
  const float* ln_g0   = (const float*)d_in[2];
  const float* ln_b0   = (const float*)d_in[3];
  const float* ln_g1   = (const float*)d_in[4];
  const float* bbw1    = (const float*)d_in[5];
  const float* bbw2    = (const float*)d_in[6];
  const float* bboutw  = (const float*)d_in[7];
  const float* latw1   = (const float*)d_in[8];
  const float* latw2   = (const float*)d_in[9];
  const float* latoutw = (const float*)d_in[10];
  const float* tg0     = (const float*)d_in[11];
  const float* tb0     = (const float*)d_in[12];
  const float* tg1     = (const float*)d_in[13];
  const float* aw1     = (const float*)d_in[14];
  const float* aw2     = (const float*)d_in[15];
  const float* vw      = (const float*)d_in[16];
  const float* ow      = (const float*)d_in[17];
  const float* fw1     = (const float*)d_in[18];
  const float* fw2     = (const float*)d_in[19];
  const float* fwg     = (const float*)d_in[20];
  const float* fv1     = (const float*)d_in[21];
  const float* ew1     = (const float*)d_in[22];
  const float* ew2     = (const float*)d_in[23];
  const float* orw1    = (const float*)d_in[24];
  const float* orw2    = (const float*)d_in[25];
  const float* outw    = (const float*)d_in[26];
  const float* sw1     = (const float*)d_in[27];
  const float* sb1     = (const float*)d_in[28];
  const float* sw2     = (const float*)d_in[29];
  const float* sb2     = (const float*)d_in[30];
  const float* sw3     = (const float*)d_in[31];
  const float* sb3     = (const float*)d_in[32];
  float* outp = (float*)d_out;

  // workspace layout
  int*    nbr    = (int*)d_ws;
  float*  ef     = (float*)((char*)d_ws + 1024*1024);
  float*  xbuf   = ef   + (size_t)NEDGE*32;
  float*  xl     = xbuf + (size_t)NRES*128;
  float*  bbf    = xl   + (size_t)NRES*128;
  float*  logits = bbf  + (size_t)NRES*28;
  float4* ca     = (float4*)(logits + (size_t)NEDGE*8);

  k_pack    <<<NRES/256, 256, 0, stream>>>(bb, ca);
  k_bbfeat  <<<NRES/256, 256, 0, stream>>>(bb, bbf);
  k_knn     <<<NRES/4,   256, 0, stream>>>(ca, nbr);
  k_edgefeat<<<NEDGE/256, 256, 0, stream>>>(ca, nbr, ef);
  k_norm    <<<NRES*32/256, 256, 0, stream>>>(latent, xl, ln_g0, ln_b0, ln_g1);
  k_init    <<<NRES/4, 256, 0, stream>>>(nbr, ef, bbf, xl, bbw1, bbw2, bboutw,
                                         latw1, latw2, latoutw, xbuf);
  for(int l=0;l<4;l++){
    k_norm   <<<NRES*32/256, 256, 0, stream>>>(xbuf, xl, tg0+l*32, tb0+l*32, tg1+l*32);
    k_logits <<<NEDGE/8, 256, 0, stream>>>(nbr, xl, ef, aw1+l*96*32, aw2+l*32*8, logits);
    k_softmax<<<NRES*8/256, 256, 0, stream>>>(logits);
    k_update <<<NRES/4, 256, 0, stream>>>(nbr, xl, logits, xbuf,
                                          vw+l*32*128, ow+l*128*32,
                                          fw1+l*32*64, fw2+l*64*32,
                                          fwg+l*64*32, fv1+l*32*32);
    k_efup   <<<NEDGE/4, 256, 0, stream>>>(nbr, xbuf, ew1+l*96*64, ew2+l*64*32, ef);
  }
  k_out<<<NRES/4, 256, 0, stream>>>(nbr, ef, xbuf, orw1, orw2, outw, outp);
  k_seq<<<NRES/4, 256, 0, stream>>>(xbuf, sw1, sb1, sw2, sb2, sw3, sb3,
                                    outp + (size_t)NRES*273);
}